// Round 2
// baseline (51.917 us; speedup 1.0000x reference)
//
#include <hip/hip_runtime.h>

// Problem constants (B=4, S=4096, DM=1024, H=16, HD=64)
#define M_TOTAL 16384
#define DMODEL  1024
#define HDIM    64
#define NHEAD   16

typedef _Float16 half8 __attribute__((ext_vector_type(8)));
typedef float    f32x4 __attribute__((ext_vector_type(4)));

// ---------------------------------------------------------------------------
// Prep: WvT[d][k] = Wv[k][d]  (f16)          [64][1024]
//       WosumT[n][d] = sum_h Wo[h*64+d][n]   [1024][64] (f16)
// Math note: scores[b,s,h,g] = q.k is constant over g (k broadcast) -> softmax
// exactly uniform -> out rows = v -> final = (x@Wv+bv)@(sum_h Wo[h*64+d][n])+bo.
// Wq/bq/Wk/bk are mathematically dead.
// ---------------------------------------------------------------------------
__global__ __launch_bounds__(256) void prep_kernel(const float* __restrict__ Wv,
                                                   const float* __restrict__ Wo,
                                                   _Float16* __restrict__ WvT,
                                                   _Float16* __restrict__ WosumT) {
    const int t = blockIdx.x * 256 + threadIdx.x;   // 0..65535
    {   // WvT: consecutive t -> consecutive d -> coalesced Wv reads
        const int d = t & 63, k = t >> 6;
        WvT[d * DMODEL + k] = (_Float16)Wv[k * HDIM + d];
    }
    {   // WosumT: consecutive t -> consecutive n -> coalesced Wo reads
        const int n = t & 1023, d = t >> 10;
        float s = 0.f;
        #pragma unroll
        for (int h = 0; h < NHEAD; ++h) s += Wo[(h * HDIM + d) * DMODEL + n];
        WosumT[n * HDIM + d] = (_Float16)s;
    }
}

// ---------------------------------------------------------------------------
// Fused main kernel. Block = 16 rows of X, 256 threads (4 waves).
// Stage whole X[16][1024] tile (f32->f16) with ONE barrier, all global loads
// issued up front (16 float4/thread in flight).
// Phase 1: V[16][64] = X @ Wv + bv; wave w owns cols [w*16, w*16+16).
// Phase 2: Out[16][1024] = V @ Wosum + bo; wave w owns cols [w*256,(w+1)*256).
// MFMA 16x16x32 f16 layouts (gfx950):
//   A: lane l holds A[l&15][(l>>4)*8 + j]   B: lane l holds B[(l>>4)*8+j][l&15]
//   C/D: lane l reg j -> row (l>>4)*4+j, col l&15
// ---------------------------------------------------------------------------
#define XH_STRIDE 1032  // 1024 halves + 16B pad: rows offset by 4 banks
#define VH_STRIDE 72

__global__ __launch_bounds__(256) void mqa_fused(const float* __restrict__ X,
                                                 const float* __restrict__ bv,
                                                 const float* __restrict__ bo,
                                                 const _Float16* __restrict__ WvT,
                                                 const _Float16* __restrict__ WosumT,
                                                 float* __restrict__ Out) {
    __shared__ _Float16 Xh[16 * XH_STRIDE];
    __shared__ _Float16 Vh[16 * VH_STRIDE];

    const int tid = threadIdx.x;
    const int l   = tid & 63;
    const int w   = tid >> 6;     // wave id 0..3
    const int lr  = l & 15;       // fragment row/col
    const int lk  = l >> 4;       // k-group 0..3
    const int m0  = blockIdx.x * 16;

    // ---- Stage whole X tile: 8 slots/thread, each slot = 8 consecutive f32 ----
    // slot = j*256 + tid; row = slot>>7 (128 slots/row), col8 = (slot&127)*8
    float4 xa[8], xb[8];
    #pragma unroll
    for (int j = 0; j < 8; ++j) {
        const int slot = j * 256 + tid;
        const int r    = slot >> 7;
        const int c    = (slot & 127) * 8;
        const float* p = &X[(size_t)(m0 + r) * DMODEL + c];
        xa[j] = *(const float4*)p;
        xb[j] = *(const float4*)(p + 4);
    }
    #pragma unroll
    for (int j = 0; j < 8; ++j) {
        const int slot = j * 256 + tid;
        const int r    = slot >> 7;
        const int c    = (slot & 127) * 8;
        union { _Float16 h[8]; half8 v; } pk;
        pk.h[0] = (_Float16)xa[j].x; pk.h[1] = (_Float16)xa[j].y;
        pk.h[2] = (_Float16)xa[j].z; pk.h[3] = (_Float16)xa[j].w;
        pk.h[4] = (_Float16)xb[j].x; pk.h[5] = (_Float16)xb[j].y;
        pk.h[6] = (_Float16)xb[j].z; pk.h[7] = (_Float16)xb[j].w;
        *(half8*)&Xh[r * XH_STRIDE + c] = pk.v;
    }
    __syncthreads();

    // ---------------- Phase 1: V = X @ Wv + bv ----------------
    f32x4 acc = {0.f, 0.f, 0.f, 0.f};
    {
        const _Float16* xp  = &Xh[lr * XH_STRIDE + lk * 8];
        const _Float16* wvp = &WvT[(size_t)(w * 16 + lr) * DMODEL + lk * 8];
        #pragma unroll 8
        for (int ks = 0; ks < 32; ++ks) {
            const half8 a = *(const half8*)(xp + ks * 32);
            const half8 b = *(const half8*)(wvp + ks * 32);
            acc = __builtin_amdgcn_mfma_f32_16x16x32_f16(a, b, acc, 0, 0, 0);
        }
    }
    // V (+bv) -> LDS as f16
    {
        const float bvv = bv[w * 16 + lr];
        #pragma unroll
        for (int j = 0; j < 4; ++j)
            Vh[(lk * 4 + j) * VH_STRIDE + w * 16 + lr] = (_Float16)(acc[j] + bvv);
    }
    __syncthreads();

    // ---------------- Phase 2: Out = V @ Wosum + bo ----------------
    const half8 a0 = *(const half8*)&Vh[lr * VH_STRIDE + lk * 8];
    const half8 a1 = *(const half8*)&Vh[lr * VH_STRIDE + 32 + lk * 8];
    #pragma unroll 4
    for (int nf = 0; nf < 16; ++nf) {
        const int n0 = w * 256 + nf * 16;
        const half8 b0 = *(const half8*)&WosumT[(size_t)(n0 + lr) * HDIM + lk * 8];
        const half8 b1 = *(const half8*)&WosumT[(size_t)(n0 + lr) * HDIM + 32 + lk * 8];
        f32x4 o = {0.f, 0.f, 0.f, 0.f};
        o = __builtin_amdgcn_mfma_f32_16x16x32_f16(a0, b0, o, 0, 0, 0);
        o = __builtin_amdgcn_mfma_f32_16x16x32_f16(a1, b1, o, 0, 0, 0);
        const float bov = bo[n0 + lr];
        #pragma unroll
        for (int j = 0; j < 4; ++j)
            Out[(size_t)(m0 + lk * 4 + j) * DMODEL + n0 + lr] = o[j] + bov;
    }
}

// ---------------------------------------------------------------------------
extern "C" void kernel_launch(void* const* d_in, const int* in_sizes, int n_in,
                              void* d_out, int out_size, void* d_ws, size_t ws_size,
                              hipStream_t stream) {
    const float* x  = (const float*)d_in[0];
    // d_in[1]=Wq, d_in[2]=bq, d_in[3]=Wk, d_in[4]=bk: mathematically dead.
    const float* Wv = (const float*)d_in[5];
    const float* bv = (const float*)d_in[6];
    const float* Wo = (const float*)d_in[7];
    const float* bo = (const float*)d_in[8];

    _Float16* WvT    = (_Float16*)d_ws;                          // 64*1024*2   = 128KB
    _Float16* WosumT = (_Float16*)((char*)d_ws + 64 * 1024 * 2); // 1024*64*2   = 128KB
    float*    out    = (float*)d_out;

    prep_kernel<<<256, 256, 0, stream>>>(Wv, Wo, WvT, WosumT);
    mqa_fused<<<M_TOTAL / 16, 256, 0, stream>>>(x, bv, bo, WvT, WosumT, out);
}